// Round 1
// baseline (423.126 us; speedup 1.0000x reference)
//
#include <hip/hip_runtime.h>

// Problem constants (from the reference):
//   B=32768 batch, T=256 trees, D=10 depth, F=512 features, C=1 leaf dim
//   LVL_PAD = T * 2^(D-1) = 131072 (row stride of nodes/biases)
constexpr int kB = 32768;
constexpr int kT = 256;
constexpr int kD = 10;
constexpr int kF = 512;
constexpr int kLvlPad = kT << (kD - 1); // 131072

// One block per batch row b (256 threads = 256 trees).
// Stage x[b, 0:512] into LDS (2 KiB), then each thread walks its tree:
//   prev = 2*t + (x[root_nodes[t]] <= root_biases[t])
//   for level i=1..9: prev = 2*prev + (x[nodes[i-1][prev]] <= biases[i-1][prev])
//   out[b, t] = leaf_nodes[prev]
__global__ __launch_bounds__(256)
void PerfectTreeTraversal_kernel(const float* __restrict__ x,
                                 const int* __restrict__ root_nodes,
                                 const float* __restrict__ root_biases,
                                 const int* __restrict__ nodes,
                                 const float* __restrict__ biases,
                                 const float* __restrict__ leaf_nodes,
                                 float* __restrict__ out)
{
    __shared__ float xs[kF];
    const int b = blockIdx.x;
    const int t = threadIdx.x;

    // Coalesced stage of the 512-float x row: 256 threads x float2.
    reinterpret_cast<float2*>(xs)[t] =
        reinterpret_cast<const float2*>(x + (size_t)b * kF)[t];
    __syncthreads();

    // Root level.
    int prev = 2 * t + (xs[root_nodes[t]] <= root_biases[t] ? 1 : 0);

    // Levels 1..D-1. Level tables are small (<=1 MiB used per level) and
    // shared by all blocks -> L2/L3 resident after warmup.
#pragma unroll
    for (int i = 1; i < kD; ++i) {
        const int*   ln = nodes  + (size_t)(i - 1) * kLvlPad;
        const float* lb = biases + (size_t)(i - 1) * kLvlPad;
        const int   f  = ln[prev];
        const float bb = lb[prev];
        prev = 2 * prev + (xs[f] <= bb ? 1 : 0);
    }

    // C == 1: one leaf value per (b, t).
    out[(size_t)b * kT + t] = leaf_nodes[prev];
}

extern "C" void kernel_launch(void* const* d_in, const int* in_sizes, int n_in,
                              void* d_out, int out_size, void* d_ws, size_t ws_size,
                              hipStream_t stream) {
    const float* x           = (const float*)d_in[0];
    const int*   root_nodes  = (const int*)d_in[1];
    const float* root_biases = (const float*)d_in[2];
    const int*   nodes       = (const int*)d_in[3];
    const float* biases      = (const float*)d_in[4];
    const float* leaf_nodes  = (const float*)d_in[5];
    float*       out         = (float*)d_out;

    PerfectTreeTraversal_kernel<<<kB, kT, 0, stream>>>(
        x, root_nodes, root_biases, nodes, biases, leaf_nodes, out);
}

// Round 2
// 145.332 us; speedup vs baseline: 2.9114x; 2.9114x over previous
//
#include <hip/hip_runtime.h>

// Problem constants (from the reference):
//   B=32768 batch, T=256 trees, D=10 depth, F=512 features, C=1 leaf dim
//   LVL_PAD = T * 2^(D-1) = 131072 (row stride of nodes/biases)
constexpr int kB = 32768;
constexpr int kT = 256;
constexpr int kD = 10;
constexpr int kF = 512;
constexpr int kLvlPad = kT << (kD - 1); // 131072
constexpr int kLevels = kD - 1;         // 9

constexpr int kRowsPerBlock  = 16;
constexpr int kTreesPerBlock = 32;
constexpr int kThreads       = kRowsPerBlock * kTreesPerBlock; // 512
constexpr int kXPad          = 516; // padded row stride in floats (2064 B, 16B-aligned)

// Prep: interleave (node, bias) so each level lookup is ONE 8B gather
// instead of two 4B gathers to separate arrays.
__global__ __launch_bounds__(256)
void pack_kernel(const int* __restrict__ nodes, const float* __restrict__ biases,
                 int2* __restrict__ packed, int n)
{
    int i = blockIdx.x * 256 + threadIdx.x;
    if (i < n)
        packed[i] = make_int2(nodes[i], __float_as_int(biases[i]));
}

// Block = 16 batch rows x 32 trees (512 threads, 1 pair/thread).
// Wave lanes: lane&15 = row, lane>>4 = tree-sub -> 16 lanes share a tree,
// so level-i gathers from that tree's 2^i-entry window coalesce.
// x rows staged in LDS; output staged in LDS for coalesced writes.
template<bool PACKED>
__global__ __launch_bounds__(kThreads, 8)
void traverse_kernel(const float* __restrict__ x,
                     const int* __restrict__ root_nodes,
                     const float* __restrict__ root_biases,
                     const int* __restrict__ nodes,
                     const float* __restrict__ biases,
                     const int2* __restrict__ packed,
                     const float* __restrict__ leaf_nodes,
                     float* __restrict__ out)
{
    __shared__ float xs[kRowsPerBlock][kXPad];
    __shared__ float outs[kRowsPerBlock][kTreesPerBlock];

    const int b0  = blockIdx.x * kRowsPerBlock;
    const int t0  = blockIdx.y * kTreesPerBlock;
    const int tid = threadIdx.x;

    // Stage 16 x-rows (2048 float4), coalesced.
    {
        const float4* xg = reinterpret_cast<const float4*>(x + (size_t)b0 * kF);
        for (int j = tid; j < kRowsPerBlock * (kF / 4); j += kThreads) {
            int r = j >> 7;   // j / 128
            int c = j & 127;
            float4 v = xg[(size_t)r * (kF / 4) + c];
            *reinterpret_cast<float4*>(&xs[r][c * 4]) = v;
        }
    }
    __syncthreads();

    const int r  = tid & (kRowsPerBlock - 1); // row within tile
    const int tt = tid >> 4;                  // tree within tile
    const int t  = t0 + tt;
    const float* __restrict__ xrow = xs[r];

    // Root level (t uniform across 16 lanes -> broadcast loads).
    int prev = 2 * t + (xrow[root_nodes[t]] <= root_biases[t] ? 1 : 0);

#pragma unroll
    for (int i = 1; i < kD; ++i) {
        int node; float bias;
        if (PACKED) {
            int2 nb = packed[(size_t)(i - 1) * kLvlPad + prev];
            node = nb.x;
            bias = __int_as_float(nb.y);
        } else {
            node = nodes [(size_t)(i - 1) * kLvlPad + prev];
            bias = biases[(size_t)(i - 1) * kLvlPad + prev];
        }
        prev = 2 * prev + (xrow[node] <= bias ? 1 : 0);
    }

    // Leaf gather (C == 1), then coalesced store via LDS.
    outs[r][tt] = leaf_nodes[prev];
    __syncthreads();

    {
        int orow = tid >> 5; // 0..15
        int ocol = tid & 31; // 0..31
        out[(size_t)(b0 + orow) * kT + (t0 + ocol)] = outs[orow][ocol];
    }
}

extern "C" void kernel_launch(void* const* d_in, const int* in_sizes, int n_in,
                              void* d_out, int out_size, void* d_ws, size_t ws_size,
                              hipStream_t stream) {
    const float* x           = (const float*)d_in[0];
    const int*   root_nodes  = (const int*)d_in[1];
    const float* root_biases = (const float*)d_in[2];
    const int*   nodes       = (const int*)d_in[3];
    const float* biases      = (const float*)d_in[4];
    const float* leaf_nodes  = (const float*)d_in[5];
    float*       out         = (float*)d_out;

    const size_t packed_bytes = (size_t)kLevels * kLvlPad * sizeof(int2); // 9.44 MB
    dim3 grid(kB / kRowsPerBlock, kT / kTreesPerBlock); // (2048, 8)

    if (ws_size >= packed_bytes) {
        const int n = kLevels * kLvlPad;
        pack_kernel<<<(n + 255) / 256, 256, 0, stream>>>(nodes, biases, (int2*)d_ws, n);
        traverse_kernel<true><<<grid, kThreads, 0, stream>>>(
            x, root_nodes, root_biases, nodes, biases,
            (const int2*)d_ws, leaf_nodes, out);
    } else {
        traverse_kernel<false><<<grid, kThreads, 0, stream>>>(
            x, root_nodes, root_biases, nodes, biases,
            nullptr, leaf_nodes, out);
    }
}